// Round 4
// baseline (206.152 us; speedup 1.0000x reference)
//
#include <hip/hip_runtime.h>
#include <hip/hip_bf16.h>
#include <hip/hip_fp16.h>

// Problem constants: B=2, N=10000, M=320000, QD=KD=HD=256, NUM_HEADS=8, dh=32.
#define DHID 256
#define NHEAD 8
#define BATCH 2

typedef _Float16 h8 __attribute__((ext_vector_type(8)));
typedef float f4 __attribute__((ext_vector_type(4)));

// ---------------- W transpose + fp16 convert: Wt[n][k] = (half)W[k][n] -----
__global__ __launch_bounds__(256) void transpose_w(
    const float* __restrict__ Wq, const float* __restrict__ Wk,
    _Float16* __restrict__ Wtq, _Float16* __restrict__ Wtk)
{
    const float* W = blockIdx.z ? Wk : Wq;
    _Float16* Wt   = blockIdx.z ? Wtk : Wtq;
    __shared__ float tile[32][33];
    const int tx = threadIdx.x;   // 0..31
    const int ty = threadIdx.y;   // 0..7
    const int n0 = blockIdx.x * 32;
    const int k0 = blockIdx.y * 32;
#pragma unroll
    for (int j = 0; j < 32; j += 8)
        tile[ty + j][tx] = W[(size_t)(k0 + ty + j) * DHID + n0 + tx];
    __syncthreads();
#pragma unroll
    for (int j = 0; j < 32; j += 8)
        Wt[(size_t)(n0 + ty + j) * DHID + k0 + tx] = (_Float16)tile[tx][ty + j];
}

// ---------------- MFMA GEMM, A-stationary --------------------------------
// grid (Mrows/64, 1, 2). Block stages its 64x256 A-tile ONCE (32 KB),
// then loops the 4 column tiles restaging only B (W^T, 128 KB, L2-hot).
__global__ __launch_bounds__(256, 2) void gemm_mfma(
    const float* __restrict__ Xq, const float* __restrict__ Xk,
    const _Float16* __restrict__ Wtq, const _Float16* __restrict__ Wtk,
    _Float16* __restrict__ Qh, _Float16* __restrict__ Kh, int Mrows)
{
    const float* X       = blockIdx.z ? Xk : Xq;
    const _Float16* Wt   = blockIdx.z ? Wtk : Wtq;
    _Float16* C          = blockIdx.z ? Kh : Qh;

    __shared__ _Float16 As[64 * 256];   // 32 KB, [row][k] swizzled
    __shared__ _Float16 Bs[64 * 256];   // 32 KB, [n][k]   swizzled

    const int t    = threadIdx.x;
    const int lane = t & 63;
    const int wave = t >> 6;
    const int rowBase = blockIdx.x * 64;

    // stage A: 64 rows x 256 k, fp32 -> fp16. chunk = 8 halves = 16B, 32/row.
#pragma unroll
    for (int i = 0; i < 8; ++i) {
        int idx = t + i * 256;          // 0..2047
        int row = idx >> 5;
        int c   = idx & 31;
        int grow = rowBase + row;
        f4 v0 = {0,0,0,0}, v1 = {0,0,0,0};
        if (grow < Mrows) {
            const float* p = X + (size_t)grow * DHID + c * 8;
            v0 = *(const f4*)p;
            v1 = *(const f4*)(p + 4);
        }
        h8 hv;
        hv[0]=(_Float16)v0[0]; hv[1]=(_Float16)v0[1]; hv[2]=(_Float16)v0[2]; hv[3]=(_Float16)v0[3];
        hv[4]=(_Float16)v1[0]; hv[5]=(_Float16)v1[1]; hv[6]=(_Float16)v1[2]; hv[7]=(_Float16)v1[3];
        int sc = c ^ (row & 7);
        *(h8*)&As[row * 256 + sc * 8] = hv;
    }

    const int ar   = wave * 16 + (lane & 15);
    const int quad = lane >> 4;

    for (int ct64 = 0; ct64 < 4; ++ct64) {
        // stage B: 64 n-rows x 256 k from fp16 Wt (contiguous 16B loads).
#pragma unroll
        for (int i = 0; i < 8; ++i) {
            int idx = t + i * 256;
            int n = idx >> 5;
            int c = idx & 31;
            h8 hv = *(const h8*)(Wt + (size_t)(ct64 * 64 + n) * DHID + c * 8);
            int sc = c ^ (n & 7);
            *(h8*)&Bs[n * 256 + sc * 8] = hv;
        }
        __syncthreads();

        f4 acc[4] = {{0,0,0,0},{0,0,0,0},{0,0,0,0},{0,0,0,0}};
#pragma unroll
        for (int kc = 0; kc < 8; ++kc) {            // K chunk of 32
            int ac = (kc * 4 + quad) ^ (ar & 7);
            h8 afrag = *(const h8*)&As[ar * 256 + ac * 8];
#pragma unroll
            for (int ct = 0; ct < 4; ++ct) {
                int bn = ct * 16 + (lane & 15);
                int bc = (kc * 4 + quad) ^ (bn & 7);
                h8 bfrag = *(const h8*)&Bs[bn * 256 + bc * 8];
                acc[ct] = __builtin_amdgcn_mfma_f32_16x16x32_f16(afrag, bfrag, acc[ct], 0, 0, 0);
            }
        }

        // epilogue: D[row=quad*4+r][col=lane&15]
#pragma unroll
        for (int ct = 0; ct < 4; ++ct) {
#pragma unroll
            for (int r = 0; r < 4; ++r) {
                int grow = rowBase + wave * 16 + quad * 4 + r;
                if (grow < Mrows)
                    C[(size_t)grow * DHID + ct64 * 64 + ct * 16 + (lane & 15)] = (_Float16)acc[ct][r];
            }
        }
        __syncthreads();
    }
}

// ---------------- Edge kernel: 16 edges/wave, 2 edges per lane ------------
// lane 8g+h owns head h (32 contiguous channels) of edges e0+g and e0+8+g:
// 16 independent 16B gathers in flight per lane (2x MLP vs round 3).
// Global max subtraction cancels in e/seg -> skipped.
__global__ __launch_bounds__(256) void edge_kernel(
    const _Float16* __restrict__ Qh, const _Float16* __restrict__ Kh,
    const int* __restrict__ mask, float* __restrict__ out,
    float* __restrict__ seg, int M, int N)
{
    const int lane = threadIdx.x & 63;
    const int wave = threadIdx.x >> 6;
    const int g = lane >> 3;        // edge-in-halfwave 0..7
    const int h = lane & 7;         // head 0..7
    const long e0 = ((long)blockIdx.x * 4 + wave) * 16;
    const int b = blockIdx.y;
    if (e0 >= M) return;

    // lanes 0..15 load 16 src indices, lanes 16..31 load 16 dst indices
    int idxv = 0;
    {
        long le = e0 + (lane & 15);
        if (le >= M) le = M - 1;
        if (lane < 16)      idxv = mask[le];
        else if (lane < 32) idxv = mask[M + le];
    }
    const int s0 = __shfl(idxv, g);
    const int s1 = __shfl(idxv, 8 + g);
    const int d0 = __shfl(idxv, 16 + g);
    const int d1 = __shfl(idxv, 24 + g);

    const _Float16* q0 = Qh + ((size_t)b * N + s0) * DHID + h * 32;
    const _Float16* q1 = Qh + ((size_t)b * N + s1) * DHID + h * 32;
    const _Float16* k0 = Kh + ((size_t)b * N + d0) * DHID + h * 32;
    const _Float16* k1 = Kh + ((size_t)b * N + d1) * DHID + h * 32;

    float t0 = 0.f, t1 = 0.f;
#pragma unroll
    for (int j = 0; j < 4; ++j) {
        h8 a0 = *(const h8*)(q0 + j * 8);
        h8 b0 = *(const h8*)(k0 + j * 8);
        h8 a1 = *(const h8*)(q1 + j * 8);
        h8 b1 = *(const h8*)(k1 + j * 8);
#pragma unroll
        for (int u = 0; u < 8; ++u) {
            t0 += (float)a0[u] * (float)b0[u];
            t1 += (float)a1[u] * (float)b1[u];
        }
    }

    const long ea = e0 + g;
    const long eb = e0 + 8 + g;
    if (ea < M) {
        float ev = expf(t0 * 0.0625f);   // 1/sqrt(256) = 1/16
        out[((size_t)b * M + ea) * NHEAD + h] = ev;
        atomicAdd(seg + ((size_t)b * N + s0) * NHEAD + h, ev);
    }
    if (eb < M) {
        float ev = expf(t1 * 0.0625f);
        out[((size_t)b * M + eb) * NHEAD + h] = ev;
        atomicAdd(seg + ((size_t)b * N + s1) * NHEAD + h, ev);
    }
}

// ---------------- Normalize: out = e / (seg[src] + 1e-16) -----------------
__global__ __launch_bounds__(256) void norm_kernel(
    const int* __restrict__ mask, const float* __restrict__ seg,
    float* __restrict__ out, int M, int N, int BM)
{
    int idx = blockIdx.x * 256 + threadIdx.x;   // idx = b*M + e
    if (idx >= BM) return;
    int b = idx / M;
    int e = idx - b * M;
    int src = mask[e];
    const float4* s4 = (const float4*)(seg + ((size_t)b * N + src) * NHEAD);
    float4 s0 = s4[0], s1 = s4[1];
    float4* o4 = (float4*)(out + (size_t)idx * NHEAD);
    float4 o0 = o4[0], o1 = o4[1];
    o0.x /= (s0.x + 1e-16f); o0.y /= (s0.y + 1e-16f);
    o0.z /= (s0.z + 1e-16f); o0.w /= (s0.w + 1e-16f);
    o1.x /= (s1.x + 1e-16f); o1.y /= (s1.y + 1e-16f);
    o1.z /= (s1.z + 1e-16f); o1.w /= (s1.w + 1e-16f);
    o4[0] = o0; o4[1] = o1;
}

extern "C" void kernel_launch(void* const* d_in, const int* in_sizes, int n_in,
                              void* d_out, int out_size, void* d_ws, size_t ws_size,
                              hipStream_t stream) {
    const float* x_q  = (const float*)d_in[0];
    const float* x_k  = (const float*)d_in[1];
    const int*   mask = (const int*)d_in[2];
    const float* w_q  = (const float*)d_in[3];
    const float* w_k  = (const float*)d_in[4];
    float* out = (float*)d_out;

    const int M = in_sizes[2] / 2;                 // 320000
    const int N = in_sizes[0] / (BATCH * DHID);    // 10000
    const int Mrows = BATCH * N;                   // 20000

    _Float16* Qh  = (_Float16*)d_ws;
    _Float16* Kh  = Qh  + (size_t)Mrows * DHID;
    _Float16* Wtq = Kh  + (size_t)Mrows * DHID;
    _Float16* Wtk = Wtq + (size_t)DHID * DHID;
    float*    seg = (float*)(Wtk + (size_t)DHID * DHID);

    hipMemsetAsync(seg, 0, (size_t)BATCH * N * NHEAD * sizeof(float), stream);

    dim3 tgrid(DHID / 32, DHID / 32, 2);
    transpose_w<<<tgrid, dim3(32, 8), 0, stream>>>(w_q, w_k, Wtq, Wtk);

    dim3 ggrid((Mrows + 63) / 64, 1, 2);
    gemm_mfma<<<ggrid, 256, 0, stream>>>(x_q, x_k, Wtq, Wtk, Qh, Kh, Mrows);

    // 16 edges per wave, 4 waves per block
    long waves = (M + 15) / 16;
    dim3 egrid((unsigned)((waves + 3) / 4), BATCH);
    edge_kernel<<<egrid, 256, 0, stream>>>(Qh, Kh, mask, out, seg, M, N);

    const int BM = BATCH * M;
    norm_kernel<<<(BM + 255) / 256, 256, 0, stream>>>(mask, seg, out, M, N, BM);
}

// Round 5
// 185.605 us; speedup vs baseline: 1.1107x; 1.1107x over previous
//
#include <hip/hip_runtime.h>
#include <hip/hip_bf16.h>
#include <hip/hip_fp16.h>

// Problem constants: B=2, N=10000, M=320000, QD=KD=HD=256, NUM_HEADS=8, dh=32.
#define DHID 256
#define NHEAD 8
#define BATCH 2

typedef _Float16 h8 __attribute__((ext_vector_type(8)));
typedef float f4 __attribute__((ext_vector_type(4)));

// ---------------- W transpose + fp16 convert: Wt[n][k] = (half)W[k][n] -----
__global__ __launch_bounds__(256) void transpose_w(
    const float* __restrict__ Wq, const float* __restrict__ Wk,
    _Float16* __restrict__ Wtq, _Float16* __restrict__ Wtk)
{
    const float* W = blockIdx.z ? Wk : Wq;
    _Float16* Wt   = blockIdx.z ? Wtk : Wtq;
    __shared__ float tile[32][33];
    const int tx = threadIdx.x;   // 0..31
    const int ty = threadIdx.y;   // 0..7
    const int n0 = blockIdx.x * 32;
    const int k0 = blockIdx.y * 32;
#pragma unroll
    for (int j = 0; j < 32; j += 8)
        tile[ty + j][tx] = W[(size_t)(k0 + ty + j) * DHID + n0 + tx];
    __syncthreads();
#pragma unroll
    for (int j = 0; j < 32; j += 8)
        Wt[(size_t)(n0 + ty + j) * DHID + k0 + tx] = (_Float16)tile[tx][ty + j];
}

// ---------------- MFMA GEMM, A-stationary (unchanged from round 3) --------
__global__ __launch_bounds__(256, 2) void gemm_mfma(
    const float* __restrict__ Xq, const float* __restrict__ Xk,
    const _Float16* __restrict__ Wtq, const _Float16* __restrict__ Wtk,
    _Float16* __restrict__ Qh, _Float16* __restrict__ Kh, int Mrows)
{
    const float* X       = blockIdx.z ? Xk : Xq;
    const _Float16* Wt   = blockIdx.z ? Wtk : Wtq;
    _Float16* C          = blockIdx.z ? Kh : Qh;

    __shared__ _Float16 As[64 * 256];   // 32 KB, [row][k] swizzled
    __shared__ _Float16 Bs[64 * 256];   // 32 KB, [n][k]   swizzled

    const int t    = threadIdx.x;
    const int lane = t & 63;
    const int wave = t >> 6;
    const int rowBase = blockIdx.x * 64;

#pragma unroll
    for (int i = 0; i < 8; ++i) {
        int idx = t + i * 256;          // 0..2047
        int row = idx >> 5;
        int c   = idx & 31;
        int grow = rowBase + row;
        f4 v0 = {0,0,0,0}, v1 = {0,0,0,0};
        if (grow < Mrows) {
            const float* p = X + (size_t)grow * DHID + c * 8;
            v0 = *(const f4*)p;
            v1 = *(const f4*)(p + 4);
        }
        h8 hv;
        hv[0]=(_Float16)v0[0]; hv[1]=(_Float16)v0[1]; hv[2]=(_Float16)v0[2]; hv[3]=(_Float16)v0[3];
        hv[4]=(_Float16)v1[0]; hv[5]=(_Float16)v1[1]; hv[6]=(_Float16)v1[2]; hv[7]=(_Float16)v1[3];
        int sc = c ^ (row & 7);
        *(h8*)&As[row * 256 + sc * 8] = hv;
    }

    const int ar   = wave * 16 + (lane & 15);
    const int quad = lane >> 4;

    for (int ct64 = 0; ct64 < 4; ++ct64) {
#pragma unroll
        for (int i = 0; i < 8; ++i) {
            int idx = t + i * 256;
            int n = idx >> 5;
            int c = idx & 31;
            h8 hv = *(const h8*)(Wt + (size_t)(ct64 * 64 + n) * DHID + c * 8);
            int sc = c ^ (n & 7);
            *(h8*)&Bs[n * 256 + sc * 8] = hv;
        }
        __syncthreads();

        f4 acc[4] = {{0,0,0,0},{0,0,0,0},{0,0,0,0},{0,0,0,0}};
#pragma unroll
        for (int kc = 0; kc < 8; ++kc) {            // K chunk of 32
            int ac = (kc * 4 + quad) ^ (ar & 7);
            h8 afrag = *(const h8*)&As[ar * 256 + ac * 8];
#pragma unroll
            for (int ct = 0; ct < 4; ++ct) {
                int bn = ct * 16 + (lane & 15);
                int bc = (kc * 4 + quad) ^ (bn & 7);
                h8 bfrag = *(const h8*)&Bs[bn * 256 + bc * 8];
                acc[ct] = __builtin_amdgcn_mfma_f32_16x16x32_f16(afrag, bfrag, acc[ct], 0, 0, 0);
            }
        }

#pragma unroll
        for (int ct = 0; ct < 4; ++ct) {
#pragma unroll
            for (int r = 0; r < 4; ++r) {
                int grow = rowBase + wave * 16 + quad * 4 + r;
                if (grow < Mrows)
                    C[(size_t)grow * DHID + ct64 * 64 + ct * 16 + (lane & 15)] = (_Float16)acc[ct][r];
            }
        }
        __syncthreads();
    }
}

// ---------------- Edge kernel: 8 edges/wave, 8 loads in flight ------------
// lane 8g+h owns head h (32 contiguous channels) of edge g. Explicit load
// phase into 8 distinct registers -> 8 independent dwordx4 gathers in
// flight per lane (round 3 had ~4; round 4's 2-edge variant halved waves).
// Global max subtraction cancels in e/seg -> skipped.
__global__ __launch_bounds__(256) void edge_kernel(
    const _Float16* __restrict__ Qh, const _Float16* __restrict__ Kh,
    const int* __restrict__ mask, float* __restrict__ out,
    float* __restrict__ seg, int M, int N)
{
    const int lane = threadIdx.x & 63;
    const int wave = threadIdx.x >> 6;
    const int g = lane >> 3;        // edge-in-wave 0..7
    const int h = lane & 7;         // head 0..7
    const long e0 = ((long)blockIdx.x * 4 + wave) * 8;
    const int b = blockIdx.y;
    if (e0 >= M) return;

    // lanes 0..7 load the 8 src indices, lanes 8..15 the 8 dst indices
    int idxv = 0;
    {
        long le = e0 + (lane & 7);
        if (le >= M) le = M - 1;
        if (lane < 8)       idxv = mask[le];
        else if (lane < 16) idxv = mask[M + le];
    }
    const int src = __shfl(idxv, g);
    const int dst = __shfl(idxv, 8 + g);

    const h8* qp = (const h8*)(Qh + ((size_t)b * N + src) * DHID + h * 32);
    const h8* kp = (const h8*)(Kh + ((size_t)b * N + dst) * DHID + h * 32);

    // ---- load phase: 8 independent 16B gathers ----
    h8 a0 = qp[0], a1 = qp[1], a2 = qp[2], a3 = qp[3];
    h8 c0 = kp[0], c1 = kp[1], c2 = kp[2], c3 = kp[3];

    // ---- compute phase ----
    float s0 = 0.f, s1 = 0.f, s2 = 0.f, s3 = 0.f;
#pragma unroll
    for (int u = 0; u < 8; ++u) {
        s0 += (float)a0[u] * (float)c0[u];
        s1 += (float)a1[u] * (float)c1[u];
        s2 += (float)a2[u] * (float)c2[u];
        s3 += (float)a3[u] * (float)c3[u];
    }
    float s = (s0 + s1) + (s2 + s3);

    const long e = e0 + g;
    if (e < M) {
        float ev = expf(s * 0.0625f);   // 1/sqrt(256) = 1/16
        out[((size_t)b * M + e) * NHEAD + h] = ev;   // 256B contiguous per wave
        atomicAdd(seg + ((size_t)b * N + src) * NHEAD + h, ev);
    }
}

// ---------------- Normalize: out = e / (seg[src] + 1e-16) -----------------
__global__ __launch_bounds__(256) void norm_kernel(
    const int* __restrict__ mask, const float* __restrict__ seg,
    float* __restrict__ out, int M, int N, int BM)
{
    int idx = blockIdx.x * 256 + threadIdx.x;   // idx = b*M + e
    if (idx >= BM) return;
    int b = idx / M;
    int e = idx - b * M;
    int src = mask[e];
    const float4* s4 = (const float4*)(seg + ((size_t)b * N + src) * NHEAD);
    float4 s0 = s4[0], s1 = s4[1];
    float4* o4 = (float4*)(out + (size_t)idx * NHEAD);
    float4 o0 = o4[0], o1 = o4[1];
    o0.x /= (s0.x + 1e-16f); o0.y /= (s0.y + 1e-16f);
    o0.z /= (s0.z + 1e-16f); o0.w /= (s0.w + 1e-16f);
    o1.x /= (s1.x + 1e-16f); o1.y /= (s1.y + 1e-16f);
    o1.z /= (s1.z + 1e-16f); o1.w /= (s1.w + 1e-16f);
    o4[0] = o0; o4[1] = o1;
}

extern "C" void kernel_launch(void* const* d_in, const int* in_sizes, int n_in,
                              void* d_out, int out_size, void* d_ws, size_t ws_size,
                              hipStream_t stream) {
    const float* x_q  = (const float*)d_in[0];
    const float* x_k  = (const float*)d_in[1];
    const int*   mask = (const int*)d_in[2];
    const float* w_q  = (const float*)d_in[3];
    const float* w_k  = (const float*)d_in[4];
    float* out = (float*)d_out;

    const int M = in_sizes[2] / 2;                 // 320000
    const int N = in_sizes[0] / (BATCH * DHID);    // 10000
    const int Mrows = BATCH * N;                   // 20000

    _Float16* Qh  = (_Float16*)d_ws;
    _Float16* Kh  = Qh  + (size_t)Mrows * DHID;
    _Float16* Wtq = Kh  + (size_t)Mrows * DHID;
    _Float16* Wtk = Wtq + (size_t)DHID * DHID;
    float*    seg = (float*)(Wtk + (size_t)DHID * DHID);

    hipMemsetAsync(seg, 0, (size_t)BATCH * N * NHEAD * sizeof(float), stream);

    dim3 tgrid(DHID / 32, DHID / 32, 2);
    transpose_w<<<tgrid, dim3(32, 8), 0, stream>>>(w_q, w_k, Wtq, Wtk);

    dim3 ggrid((Mrows + 63) / 64, 1, 2);
    gemm_mfma<<<ggrid, 256, 0, stream>>>(x_q, x_k, Wtq, Wtk, Qh, Kh, Mrows);

    // 8 edges per wave, 4 waves per block
    long waves = (M + 7) / 8;
    dim3 egrid((unsigned)((waves + 3) / 4), BATCH);
    edge_kernel<<<egrid, 256, 0, stream>>>(Qh, Kh, mask, out, seg, M, N);

    const int BM = BATCH * M;
    norm_kernel<<<(BM + 255) / 256, 256, 0, stream>>>(mask, seg, out, M, N, BM);
}